// Round 8
// baseline (5008.990 us; speedup 1.0000x reference)
//
#include <hip/hip_runtime.h>

#define B_ 1024
#define T_ 100
#define F_ 300
#define FP_ 320
#define U_ 512
#define G4_ 2048
#define C_ 10
#define EPS_ 1e-3f

typedef _Float16 f16x8 __attribute__((ext_vector_type(8)));
typedef float f32x4 __attribute__((ext_vector_type(4)));

typedef __attribute__((address_space(1))) const void* gcptr_t;
typedef __attribute__((address_space(3))) void* lptr_t;

__device__ __forceinline__ void async_ld16(_Float16* lds, const _Float16* g) {
  __builtin_amdgcn_global_load_lds((gcptr_t)g, (lptr_t)lds, 16, 0, 0);
}

// agent-scope (sc1: L2-bypass, coherent at L3) accessors — R6/R7-validated
__device__ __forceinline__ float ld_agent_f32(const float* p) {
  return __hip_atomic_load(p, __ATOMIC_RELAXED, __HIP_MEMORY_SCOPE_AGENT);
}
__device__ __forceinline__ void st_agent_f32(float* p, float v) {
  __hip_atomic_store(p, v, __ATOMIC_RELAXED, __HIP_MEMORY_SCOPE_AGENT);
}

// ---------------- prep: length sort (descending) + active-count table ----------
// perm[i] = original batch row of compact row i (sorted by len desc).
// nt[t]   = #rows with len > t (active rows at step t occupy prefix [0, nt[t])).
__global__ __launch_bounds__(1024) void prep_kernel(const int* __restrict__ mask,
                                                    int* __restrict__ perm,
                                                    int* __restrict__ nt) {
  __shared__ int cnt[T_ + 1];
  __shared__ int start[T_ + 1];
  int b = threadIdx.x;
  if (b <= T_) cnt[b] = 0;
  __syncthreads();
  const int* mrow = mask + (size_t)b * T_;
  int len = 0;
  for (int t = 0; t < T_; t++) len += mrow[t];
  atomicAdd(&cnt[len], 1);
  __syncthreads();
  if (b == 0) {
    int run = 0;
    for (int l = T_; l >= 0; l--) {
      start[l] = run;  // #rows with len > l
      run += cnt[l];
    }
  }
  __syncthreads();
  if (b < T_) nt[b] = start[b];
  __syncthreads();
  int pos = atomicAdd(&start[len], 1);
  perm[pos] = b;
}

// ---------------- prologue kernels ----------------

// x (B,T,F) fp32 -> x_hi/x_lo [T][compact i][FP_] fp16 split, zero-padded F..FP_
__global__ __launch_bounds__(256) void cast_x_kernel(const float* __restrict__ x,
                                                     const int* __restrict__ perm,
                                                     const int* __restrict__ nt,
                                                     _Float16* __restrict__ xhi,
                                                     _Float16* __restrict__ xlo) {
  size_t cidx = (size_t)blockIdx.x * 256 + threadIdx.x;  // [T*B*FP_/8)
  int fc = (int)(cidx % (FP_ / 8));
  size_t bt = cidx / (FP_ / 8);
  int i = (int)(bt % B_);
  int t = (int)(bt / B_);
  int nr = (nt[t] + 127) & ~127;
  if (i >= nr) return;
  int b = perm[i];
  int f = fc * 8;
  const float* xr = x + ((size_t)b * T_ + t) * F_;
  float v[8];
  if (f + 8 <= F_) {
    float4 a = *(const float4*)(xr + f);
    float4 c = *(const float4*)(xr + f + 4);
    v[0] = a.x; v[1] = a.y; v[2] = a.z; v[3] = a.w;
    v[4] = c.x; v[5] = c.y; v[6] = c.z; v[7] = c.w;
  } else {
#pragma unroll
    for (int j = 0; j < 8; j++) v[j] = (f + j < F_) ? xr[f + j] : 0.f;
  }
  f16x8 hi, lo;
#pragma unroll
  for (int j = 0; j < 8; j++) {
    _Float16 h = (_Float16)v[j];
    hi[j] = h;
    lo[j] = (_Float16)(v[j] - (float)h);
  }
  *(f16x8*)(xhi + cidx * 8) = hi;
  *(f16x8*)(xlo + cidx * 8) = lo;
}

// W [K][N] fp32 -> Wt_hi/Wt_lo [N][Kp] fp16 split (transposed, zero-padded K..Kp)
__global__ __launch_bounds__(256) void cast_w_kernel(const float* __restrict__ W,
                                                     _Float16* __restrict__ Whi,
                                                     _Float16* __restrict__ Wlo,
                                                     int K, int N, int Kp) {
  __shared__ float tile[32][33];
  int n0 = blockIdx.x * 32, k0 = blockIdx.y * 32;
  int tx = threadIdx.x & 31, ty = threadIdx.x >> 5;
#pragma unroll
  for (int r = 0; r < 32; r += 8) {
    int k = k0 + ty + r;
    tile[ty + r][tx] = (k < K) ? W[(size_t)k * N + n0 + tx] : 0.f;
  }
  __syncthreads();
#pragma unroll
  for (int r = 0; r < 32; r += 8) {
    int n = n0 + ty + r, kk = k0 + tx;
    if (kk < Kp) {
      float v = tile[tx][ty + r];
      _Float16 h = (_Float16)v;
      Whi[(size_t)n * Kp + kk] = h;
      Wlo[(size_t)n * Kp + kk] = (_Float16)(v - (float)h);
    }
  }
}

// ---------------- per-step kernel: 256 co-resident blocks ----------------
// One dispatch per step. 256 blocks (<=1 per CU by capacity -> all co-resident,
// any flag order is deadlock-free), 64 KB LDS, 512 threads. Each block
// grid-strides an EXACT tile list (no inactive slots), posting a per-(op,m-slab)
// done flag after each tile; then grid-strides cells, spinning on the flags of
// the slabs they consume (R7-verified mechanism). Gemm is single-buffered
// (4 planes x 16 KB = 64 KB); cells reuse the gemm LDS for reduction scratch.
// Segment starts are multiples of 16 so XCD = bid%8 = n%8: each XCD reads only
// its 1/8 N-slice of the weights (no B duplication in L2).

struct CellP {
  const float *Gx, *Gh, *bias, *kg, *kb, *rg, *rb, *sg, *sb;
  float* cS;
  _Float16* hP;  // hi plane; lo at +B_*U_
  float* outb;   // layer-1 only (else null)
};
struct StepP {
  const _Float16 *A0, *A1, *A3;  // A bases for ops 0/2, 1, 3 (hi; lo at +aLo)
  const _Float16 *W0t, *R0t, *W1t, *R1t;
  float *G0x, *G0h, *G1x, *G1h;
  const int* nt;
  int* dn;  // this dispatch's [4][8] tile-done counters (pre-zeroed)
  int t;
  CellP c0, c1;
};

__device__ __forceinline__ void wait_flag(const int* f) {
  while (__hip_atomic_load(f, __ATOMIC_RELAXED, __HIP_MEMORY_SCOPE_AGENT) < 16)
    __builtin_amdgcn_s_sleep(1);
}

// single-buffered 128x128 split-fp16 gemm tile (BK=64, 8 waves, wave tile 64x32)
// MFMA order per accumulator identical to R3/R7 -> bit-identical results.
__device__ __forceinline__ void gemm_tile(const _Float16* Ah, size_t aLo,
                                          const _Float16* Bh, const _Float16* Bl,
                                          float* __restrict__ G, int lda, int K,
                                          int mBase, int nBase, _Float16* lds,
                                          int tid) {
  const int w = tid >> 6;   // 0..7
  const int lane = tid & 63;
  const int wm = (w & 1) << 6;   // wave row offset (0/64)
  const int wn = (w >> 1) << 5;  // wave col offset (0/32/64/96)
  const int i0 = w << 1;

  f32x4 acc[4][2];
#pragma unroll
  for (int mt = 0; mt < 4; mt++)
#pragma unroll
    for (int nt2 = 0; nt2 < 2; nt2++) acc[mt][nt2] = (f32x4){0.f, 0.f, 0.f, 0.f};

  const int nch = K >> 6;
#pragma unroll 1
  for (int c = 0; c < nch; c++) {
    int k0 = c << 6;
#pragma unroll
    for (int j = 0; j < 2; j++) {
      int i = i0 + j;
      int idx = (i << 6) + lane;
      int row = idx >> 3;
      int cl = ((idx & 7) ^ (row & 7)) << 3;
      size_t aoff = (size_t)(mBase + row) * lda + k0 + cl;
      size_t boff = (size_t)(nBase + row) * K + k0 + cl;
      async_ld16(lds + (i << 9), Ah + aoff);
      async_ld16(lds + 8192 + (i << 9), Ah + aLo + aoff);
      async_ld16(lds + 16384 + (i << 9), Bh + boff);
      async_ld16(lds + 24576 + (i << 9), Bl + boff);
    }
    __syncthreads();  // drains staging (vmcnt 0 at barrier)
    const _Float16* ash = lds;
    const _Float16* asl = lds + 8192;
    const _Float16* bsh = lds + 16384;
    const _Float16* bsl = lds + 24576;
#pragma unroll
    for (int q = 0; q < 2; q++) {
      f16x8 afh[4], afl[4], bfh[2], bfl[2];
#pragma unroll
      for (int mt = 0; mt < 4; mt++) {
        int row = wm + (mt << 4) + (lane & 15);
        int p = ((q << 2) + (lane >> 4)) ^ (row & 7);
        afh[mt] = *(const f16x8*)&ash[(row << 6) + (p << 3)];
        afl[mt] = *(const f16x8*)&asl[(row << 6) + (p << 3)];
      }
#pragma unroll
      for (int nt2 = 0; nt2 < 2; nt2++) {
        int row = wn + (nt2 << 4) + (lane & 15);
        int p = ((q << 2) + (lane >> 4)) ^ (row & 7);
        bfh[nt2] = *(const f16x8*)&bsh[(row << 6) + (p << 3)];
        bfl[nt2] = *(const f16x8*)&bsl[(row << 6) + (p << 3)];
      }
      __builtin_amdgcn_s_setprio(1);
#pragma unroll
      for (int mt = 0; mt < 4; mt++)
#pragma unroll
        for (int nt2 = 0; nt2 < 2; nt2++) {
          acc[mt][nt2] = __builtin_amdgcn_mfma_f32_16x16x32_f16(afh[mt], bfh[nt2], acc[mt][nt2], 0, 0, 0);
          acc[mt][nt2] = __builtin_amdgcn_mfma_f32_16x16x32_f16(afl[mt], bfh[nt2], acc[mt][nt2], 0, 0, 0);
          acc[mt][nt2] = __builtin_amdgcn_mfma_f32_16x16x32_f16(afh[mt], bfl[nt2], acc[mt][nt2], 0, 0, 0);
        }
      __builtin_amdgcn_s_setprio(0);
    }
    __syncthreads();  // guards buffer reuse next chunk
  }

  // C/D layout: col = lane&15, row = (lane>>4)*4 + reg ; sc1 stores
  int q4 = lane >> 4, cc = lane & 15;
#pragma unroll
  for (int mt = 0; mt < 4; mt++)
#pragma unroll
    for (int nt2 = 0; nt2 < 2; nt2++)
#pragma unroll
      for (int r = 0; r < 4; r++) {
        int row = mBase + wm + (mt << 4) + (q4 << 2) + r;
        int col = nBase + wn + (nt2 << 4) + cc;
        st_agent_f32(&G[(size_t)row * G4_ + col], acc[mt][nt2][r]);
      }
}

__device__ __forceinline__ void block_reduce8(float* v, int n, float (*sred)[4], int tid) {
  int lane = tid & 63, wv = tid >> 6;
  for (int off = 32; off > 0; off >>= 1)
    for (int i = 0; i < n; i++) v[i] += __shfl_down(v[i], off, 64);
  if (lane == 0)
    for (int i = 0; i < n; i++) sred[wv][i] = v[i];
  __syncthreads();
  if (tid == 0) {
    for (int i = 0; i < n; i++) {
      float a = 0.f;
      for (int k2 = 0; k2 < 8; k2++) a += sred[k2][i];
      sred[8][i] = a;
    }
  }
  __syncthreads();
  for (int i = 0; i < n; i++) v[i] = sred[8][i];
}

__device__ __forceinline__ float sigm(float x) { return 1.f / (1.f + expf(-x)); }

// R4/R7-verified 512-thread cell; G reads via sc1 (same-dispatch producer).
__device__ __forceinline__ void do_cell(const CellP& cp, int row, int tid,
                                        float (*sred)[4]) {
  const float* gx = cp.Gx + (size_t)row * G4_;
  const float* gh = cp.Gh + (size_t)row * G4_;
  float vx[4], vh[4];
  float s[4] = {0.f, 0.f, 0.f, 0.f};
#pragma unroll
  for (int i = 0; i < 4; i++) {
    int col = tid + (i << 9);
    float a = ld_agent_f32(&gx[col]), d = ld_agent_f32(&gh[col]);
    vx[i] = a;
    vh[i] = d;
    s[0] += a;
    s[1] += a * a;
    s[2] += d;
    s[3] += d * d;
  }
  block_reduce8(s, 4, sred, tid);
  const float inv = 1.f / 2048.f;
  float m1 = s[0] * inv, m2 = s[2] * inv;
  float rs1 = rsqrtf(fmaxf(s[1] * inv - m1 * m1, 0.f) + EPS_);
  float rs2 = rsqrtf(fmaxf(s[3] * inv - m2 * m2, 0.f) + EPS_);
  float z[4];  // 0:i 1:f 2:g 3:o
#pragma unroll
  for (int i = 0; i < 4; i++) {
    int col = tid + (i << 9);
    z[i] = (vx[i] - m1) * rs1 * cp.kg[col] + cp.kb[col] +
           (vh[i] - m2) * rs2 * cp.rg[col] + cp.rb[col] + cp.bias[col];
  }
  size_t base = (size_t)row * U_ + tid;
  float co = cp.cS[base];
  float cn = sigm(z[1]) * co + sigm(z[0]) * tanhf(z[2]);
  float t2[4] = {cn, cn * cn, 0.f, 0.f};
  block_reduce8(t2, 2, sred, tid);
  const float invU = 1.f / 512.f;
  float mc = t2[0] * invU;
  float rsc = rsqrtf(fmaxf(t2[1] * invU - mc * mc, 0.f) + EPS_);
  float cl = (cn - mc) * rsc * cp.sg[tid] + cp.sb[tid];
  float hn = sigm(z[3]) * tanhf(cl);
  _Float16 hh = (_Float16)hn;
  cp.hP[base] = hh;
  cp.hP[base + (size_t)B_ * U_] = (_Float16)(hn - (float)hh);
  cp.cS[base] = cl;
  if (cp.outb) cp.outb[base] = hn;  // layer-1: freezes at last active step
}

#define NBK_ 256

__global__ __launch_bounds__(512, 1) void step_kernel(StepP S) {
  __shared__ __align__(16) _Float16 lds[4][8192];  // 64 KB
  const int tid = threadIdx.x;
  const int bid = blockIdx.x;
  const int t = S.t;
  const int nt0 = (t >= 0) ? S.nt[t] : 0;
  const int ntN = (t + 1 < T_) ? S.nt[t + 1] : 0;
  const int mb0 = (nt0 + 127) >> 7;
  const int mbN = (ntN + 127) >> 7;

  // exact tile list; segment starts are multiples of 16 (XCD = n%8 locality)
  const int s0 = mb0 << 4;                       // op0
  const int s01 = s0 << 1;                       // + op1
  const int nOp2 = (t >= 0) ? (mbN << 4) : 0;    // op2 (inactive at prime)
  const int s012 = s01 + nOp2;
  const int ntile = s012 + (mbN << 4);           // + op3

  const size_t hLo = (size_t)B_ * U_;
  for (int tl = bid; tl < ntile; tl += NBK_) {
    int op, rem;
    if (tl < s0) { op = 0; rem = tl; }
    else if (tl < s01) { op = 1; rem = tl - s0; }
    else if (tl < s012) { op = 2; rem = tl - s01; }
    else { op = 3; rem = tl - s012; }
    int m = rem >> 4, n = rem & 15;
    const _Float16 *Ah, *Bh, *Bl;
    size_t aLo;
    float* G;
    int lda, K;
    if (op == 0) {        // G1x(t) = h0(t) @ W1
      Ah = S.A0; aLo = hLo; Bh = S.W1t; Bl = S.W1t + (size_t)G4_ * U_;
      G = S.G1x; lda = U_; K = U_;
    } else if (op == 1) { // G1h(t) = h1(t-1) @ R1
      Ah = S.A1; aLo = hLo; Bh = S.R1t; Bl = S.R1t + (size_t)G4_ * U_;
      G = S.G1h; lda = U_; K = U_;
    } else if (op == 2) { // G0h(t+1) = h0(t) @ R0
      Ah = S.A0; aLo = hLo; Bh = S.R0t; Bl = S.R0t + (size_t)G4_ * U_;
      G = S.G0h; lda = U_; K = U_;
    } else {              // G0x(t+1) = x(t+1) @ W0
      Ah = S.A3; aLo = (size_t)T_ * B_ * FP_;
      Bh = S.W0t; Bl = S.W0t + (size_t)G4_ * FP_;
      G = S.G0x; lda = FP_; K = FP_;
    }
    gemm_tile(Ah, aLo, Bh, Bl, G, lda, K, m << 7, n << 7, &lds[0][0], tid);
    asm volatile("s_waitcnt vmcnt(0)" ::: "memory");  // sc1 stores visible
    __syncthreads();
    if (tid == 0)
      __hip_atomic_fetch_add(S.dn + op * 8 + m, 1, __ATOMIC_RELAXED,
                             __HIP_MEMORY_SCOPE_AGENT);
  }

  // cells (gemm LDS reused as reduction scratch; this block's gemm is done)
  float (*sred)[4] = (float(*)[4]) & lds[0][0];
  const int total = nt0 + ntN;
  for (int j = bid; j < total; j += NBK_) {
    if (j < nt0) {  // cell1(t): needs op0 & op1 slab m
      int m = j >> 7;
      if (tid == 0) {
        wait_flag(S.dn + 0 * 8 + m);
        wait_flag(S.dn + 1 * 8 + m);
      }
      __syncthreads();
      do_cell(S.c1, j, tid, sred);
    } else {  // cell0(t+1): needs op3 (& op2 when t>=0) slab m
      int j2 = j - nt0;
      int m = j2 >> 7;
      if (tid == 0) {
        wait_flag(S.dn + 3 * 8 + m);
        if (t >= 0) wait_flag(S.dn + 2 * 8 + m);
      }
      __syncthreads();
      do_cell(S.c0, j2, tid, sred);
    }
    __syncthreads();  // sred reuse guard across grid-stride iterations
  }
}

// ---------------- final dense + softmax (scatter through perm) ----------------
__global__ __launch_bounds__(64) void dense_softmax_kernel(const float* __restrict__ outb,
                                                           const float* __restrict__ Wd,
                                                           const float* __restrict__ bd,
                                                           const int* __restrict__ perm,
                                                           float* __restrict__ o) {
  int b = blockIdx.x, lane = threadIdx.x;
  __shared__ float sl[16];
  int col = lane & 15, kg = lane >> 4;
  float acc = 0.f;
  if (col < C_) {
    for (int k = kg; k < U_; k += 4) acc += outb[(size_t)b * U_ + k] * Wd[(size_t)k * C_ + col];
  }
  acc += __shfl_down(acc, 16, 64);
  acc += __shfl_down(acc, 32, 64);
  if (lane < C_) sl[lane] = acc + bd[lane];
  __syncthreads();
  if (lane < C_) {
    float mx = sl[0];
    for (int i = 1; i < C_; i++) mx = fmaxf(mx, sl[i]);
    float ssum = 0.f;
    for (int i = 0; i < C_; i++) ssum += expf(sl[i] - mx);
    o[(size_t)perm[b] * C_ + lane] = expf(sl[lane] - mx) / ssum;
  }
}

// ---------------- host ----------------

extern "C" void kernel_launch(void* const* d_in, const int* in_sizes, int n_in,
                              void* d_out, int out_size, void* d_ws, size_t ws_size,
                              hipStream_t stream) {
  const float* x = (const float*)d_in[0];
  const int* mask = (const int*)d_in[1];
  const float* W0 = (const float*)d_in[2];
  const float* R0 = (const float*)d_in[3];
  const float* b0 = (const float*)d_in[4];
  const float* kg0 = (const float*)d_in[5];
  const float* kb0 = (const float*)d_in[6];
  const float* rg0 = (const float*)d_in[7];
  const float* rb0 = (const float*)d_in[8];
  const float* sg0 = (const float*)d_in[9];
  const float* sb0 = (const float*)d_in[10];
  const float* W1 = (const float*)d_in[11];
  const float* R1 = (const float*)d_in[12];
  const float* b1 = (const float*)d_in[13];
  const float* kg1 = (const float*)d_in[14];
  const float* kb1 = (const float*)d_in[15];
  const float* rg1 = (const float*)d_in[16];
  const float* rb1 = (const float*)d_in[17];
  const float* sg1 = (const float*)d_in[18];
  const float* sb1 = (const float*)d_in[19];
  const float* Wd = (const float*)d_in[20];
  const float* bd = (const float*)d_in[21];
  float* out = (float*)d_out;

  const size_t HS = (size_t)2 * B_ * U_;  // f16 elems per h parity (hi+lo)

  char* w = (char*)d_ws;
  size_t o = 0;
  auto alloc = [&](size_t bytes) {
    size_t r = o;
    o += (bytes + 255) & ~(size_t)255;
    return r;
  };
  // zero region (contiguous, first): states + h (both parities) + G0h + flags
  size_t o_c0s = alloc((size_t)B_ * U_ * 4);
  size_t o_c1s = alloc((size_t)B_ * U_ * 4);
  size_t o_outf = alloc((size_t)B_ * U_ * 4);
  size_t o_h0p = alloc(HS * 2 * 2);  // 2 parities x (hi+lo) f16
  size_t o_h1p = alloc(HS * 2 * 2);
  size_t o_G0h = alloc((size_t)B_ * G4_ * 4);
  size_t o_dn = alloc((size_t)(T_ + 1) * 4 * 8 * 4);
  size_t zero_bytes = o;
  size_t o_xh = alloc((size_t)T_ * B_ * FP_ * 2 * 2);  // hi + lo
  size_t o_W0t = alloc((size_t)G4_ * FP_ * 2 * 2);
  size_t o_R0t = alloc((size_t)G4_ * U_ * 2 * 2);
  size_t o_W1t = alloc((size_t)G4_ * U_ * 2 * 2);
  size_t o_R1t = alloc((size_t)G4_ * U_ * 2 * 2);
  size_t o_G0x = alloc((size_t)B_ * G4_ * 4);
  size_t o_G1x = alloc((size_t)B_ * G4_ * 4);
  size_t o_G1h = alloc((size_t)B_ * G4_ * 4);
  size_t o_perm = alloc((size_t)B_ * 4);
  size_t o_nt = alloc((size_t)T_ * 4);
  (void)ws_size;

  float* c0s = (float*)(w + o_c0s);
  float* c1s = (float*)(w + o_c1s);
  float* outf = (float*)(w + o_outf);
  _Float16* h0p = (_Float16*)(w + o_h0p);
  _Float16* h1p = (_Float16*)(w + o_h1p);
  float* G0h = (float*)(w + o_G0h);
  int* dnp = (int*)(w + o_dn);
  _Float16* xh = (_Float16*)(w + o_xh);
  _Float16* W0t = (_Float16*)(w + o_W0t);
  _Float16* R0t = (_Float16*)(w + o_R0t);
  _Float16* W1t = (_Float16*)(w + o_W1t);
  _Float16* R1t = (_Float16*)(w + o_R1t);
  float* G0x = (float*)(w + o_G0x);
  float* G1x = (float*)(w + o_G1x);
  float* G1h = (float*)(w + o_G1h);
  int* perm = (int*)(w + o_perm);
  int* ntp = (int*)(w + o_nt);

  hipMemsetAsync(w, 0, zero_bytes, stream);

  prep_kernel<<<1, 1024, 0, stream>>>(mask, perm, ntp);

  {
    size_t chunks = (size_t)T_ * B_ * (FP_ / 8);
    cast_x_kernel<<<dim3((unsigned)(chunks / 256)), 256, 0, stream>>>(
        x, perm, ntp, xh, xh + (size_t)T_ * B_ * FP_);
  }
  cast_w_kernel<<<dim3(G4_ / 32, FP_ / 32), 256, 0, stream>>>(
      W0, W0t, W0t + (size_t)G4_ * FP_, F_, G4_, FP_);
  cast_w_kernel<<<dim3(G4_ / 32, U_ / 32), 256, 0, stream>>>(
      R0, R0t, R0t + (size_t)G4_ * U_, U_, G4_, U_);
  cast_w_kernel<<<dim3(G4_ / 32, U_ / 32), 256, 0, stream>>>(
      W1, W1t, W1t + (size_t)G4_ * U_, U_, G4_, U_);
  cast_w_kernel<<<dim3(G4_ / 32, U_ / 32), 256, 0, stream>>>(
      R1, R1t, R1t + (size_t)G4_ * U_, U_, G4_, U_);

  // one dispatch per step: t = -1 (prime: op3 + cell0(0)) .. T-1 (tail: ops0/1 + cell1)
  for (int t = -1; t < T_; t++) {
    StepP S;
    S.A0 = h0p + (size_t)(t & 1) * HS;        // h0(t)   (unused at t=-1)
    S.A1 = h1p + (size_t)((t + 1) & 1) * HS;  // h1(t-1) (zeros at t=0: parity-1 pre-zeroed)
    S.A3 = xh + (size_t)(t + 1) * B_ * FP_;   // x(t+1)  (unused at t=T-1)
    S.W0t = W0t; S.R0t = R0t; S.W1t = W1t; S.R1t = R1t;
    S.G0x = G0x; S.G0h = G0h; S.G1x = G1x; S.G1h = G1h;
    S.nt = ntp;
    S.dn = dnp + (size_t)(t + 1) * 32;
    S.t = t;
    S.c0 = CellP{G0x, G0h, b0, kg0, kb0, rg0, rb0, sg0, sb0,
                 c0s, h0p + (size_t)((t + 1) & 1) * HS, nullptr};
    S.c1 = CellP{G1x, G1h, b1, kg1, kb1, rg1, rb1, sg1, sb1,
                 c1s, h1p + (size_t)((t < 0 ? 0 : t) & 1) * HS, outf};
    step_kernel<<<NBK_, 512, 0, stream>>>(S);
  }

  dense_softmax_kernel<<<B_, 64, 0, stream>>>(outf, Wd, bd, perm, out);
}

// Round 9
// 3715.830 us; speedup vs baseline: 1.3480x; 1.3480x over previous
//
#include <hip/hip_runtime.h>

#define B_ 1024
#define T_ 100
#define F_ 300
#define FP_ 320
#define U_ 512
#define G4_ 2048
#define C_ 10
#define EPS_ 1e-3f

typedef _Float16 f16x8 __attribute__((ext_vector_type(8)));
typedef float f32x4 __attribute__((ext_vector_type(4)));

typedef __attribute__((address_space(1))) const void* gcptr_t;
typedef __attribute__((address_space(3))) void* lptr_t;

__device__ __forceinline__ void async_ld16(_Float16* lds, const _Float16* g) {
  __builtin_amdgcn_global_load_lds((gcptr_t)g, (lptr_t)lds, 16, 0, 0);
}

// ---------------- prep: length sort (descending) + active-count table ----------
// perm[i] = original batch row of compact row i (sorted by len desc).
// nt[t]   = #rows with len > t (active rows at step t occupy prefix [0, nt[t])).
__global__ __launch_bounds__(1024) void prep_kernel(const int* __restrict__ mask,
                                                    int* __restrict__ perm,
                                                    int* __restrict__ nt) {
  __shared__ int cnt[T_ + 1];
  __shared__ int start[T_ + 1];
  int b = threadIdx.x;
  if (b <= T_) cnt[b] = 0;
  __syncthreads();
  const int* mrow = mask + (size_t)b * T_;
  int len = 0;
  for (int t = 0; t < T_; t++) len += mrow[t];
  atomicAdd(&cnt[len], 1);
  __syncthreads();
  if (b == 0) {
    int run = 0;
    for (int l = T_; l >= 0; l--) {
      start[l] = run;  // #rows with len > l
      run += cnt[l];
    }
  }
  __syncthreads();
  if (b < T_) nt[b] = start[b];
  __syncthreads();
  int pos = atomicAdd(&start[len], 1);
  perm[pos] = b;
}

// ---------------- prologue kernels ----------------

// x (B,T,F) fp32 -> x_hi/x_lo [T][compact i][FP_] fp16 split, zero-padded F..FP_
__global__ __launch_bounds__(256) void cast_x_kernel(const float* __restrict__ x,
                                                     const int* __restrict__ perm,
                                                     const int* __restrict__ nt,
                                                     _Float16* __restrict__ xhi,
                                                     _Float16* __restrict__ xlo) {
  size_t cidx = (size_t)blockIdx.x * 256 + threadIdx.x;  // [T*B*FP_/8)
  int fc = (int)(cidx % (FP_ / 8));
  size_t bt = cidx / (FP_ / 8);
  int i = (int)(bt % B_);
  int t = (int)(bt / B_);
  int nr = (nt[t] + 127) & ~127;
  if (i >= nr) return;
  int b = perm[i];
  int f = fc * 8;
  const float* xr = x + ((size_t)b * T_ + t) * F_;
  float v[8];
  if (f + 8 <= F_) {
    float4 a = *(const float4*)(xr + f);
    float4 c = *(const float4*)(xr + f + 4);
    v[0] = a.x; v[1] = a.y; v[2] = a.z; v[3] = a.w;
    v[4] = c.x; v[5] = c.y; v[6] = c.z; v[7] = c.w;
  } else {
#pragma unroll
    for (int j = 0; j < 8; j++) v[j] = (f + j < F_) ? xr[f + j] : 0.f;
  }
  f16x8 hi, lo;
#pragma unroll
  for (int j = 0; j < 8; j++) {
    _Float16 h = (_Float16)v[j];
    hi[j] = h;
    lo[j] = (_Float16)(v[j] - (float)h);
  }
  *(f16x8*)(xhi + cidx * 8) = hi;
  *(f16x8*)(xlo + cidx * 8) = lo;
}

// W [K][N] fp32 -> Wt_hi/Wt_lo [N][Kp] fp16 split (transposed, zero-padded K..Kp)
__global__ __launch_bounds__(256) void cast_w_kernel(const float* __restrict__ W,
                                                     _Float16* __restrict__ Whi,
                                                     _Float16* __restrict__ Wlo,
                                                     int K, int N, int Kp) {
  __shared__ float tile[32][33];
  int n0 = blockIdx.x * 32, k0 = blockIdx.y * 32;
  int tx = threadIdx.x & 31, ty = threadIdx.x >> 5;
#pragma unroll
  for (int r = 0; r < 32; r += 8) {
    int k = k0 + ty + r;
    tile[ty + r][tx] = (k < K) ? W[(size_t)k * N + n0 + tx] : 0.f;
  }
  __syncthreads();
#pragma unroll
  for (int r = 0; r < 32; r += 8) {
    int n = n0 + ty + r, kk = k0 + tx;
    if (kk < Kp) {
      float v = tile[tx][ty + r];
      _Float16 h = (_Float16)v;
      Whi[(size_t)n * Kp + kk] = h;
      Wlo[(size_t)n * Kp + kk] = (_Float16)(v - (float)h);
    }
  }
}

// ---------------- GEMM phase: up to 4 independent ops, one per blockIdx.z ----------
// G = A (MxK) * Bt^T (Bt is [N][K]) -> G [M][2048] fp32.
// Split-fp16 merged single K-pass: per 64-K chunk all 4 planes (A_hi, A_lo,
// B_hi, B_lo) staged, 3 MFMA combos Ah*Bh + Al*Bh + Ah*Bl.
// Double-buffered LDS (2 x 64 KB = 128 KB), COUNTED-vmcnt schedule (T3/T4):
//   issue STAGE(c+1) -> s_waitcnt vmcnt(8) (chunk c's 8/wave loads done;
//   c+1's stay in flight) -> s_barrier -> ds_read+MFMA(c) -> s_barrier.
// No vmcnt(0) in the main loop (replaces __syncthreads' full drain = the
// m97-structure stall). MFMA operands SWAPPED: mfma(bf, af) gives each lane
// 4 consecutive N-columns per acc -> coalesced float4 C-write. Same products,
// same accumulation order -> bit-identical G.
// M-blocks with mBase >= nt[step] early-exit (rows past end-of-sequence).
struct GemmOp {
  const _Float16* A;   // hi plane; lo plane at A + aLo
  const _Float16* Bt;  // hi plane; lo plane at Bt + G4_*K
  float* G;
  int lda;
  int K;
  size_t aLo;
  int step;
};
struct G4Pack {
  GemmOp op[4];
  const int* nt;
};

__global__ __launch_bounds__(512, 1) void gemm_phase(G4Pack P) {
  GemmOp op = P.op[blockIdx.z];
  const int mBase = blockIdx.y * 128, nBase = blockIdx.x * 128;
  if (mBase >= P.nt[op.step]) return;  // block-uniform: safe before barriers
  const int K = op.K, lda = op.lda;
  const _Float16* Ah = op.A;
  const _Float16* Al = op.A + op.aLo;
  const _Float16* Bh = op.Bt;
  const _Float16* Bl = op.Bt + (size_t)G4_ * K;

  // 2 buffers x 4 planes x (128 x 64) f16 = 128 KB
  __shared__ __align__(16) _Float16 lds[2][4][128 * 64];

  const int tid = threadIdx.x;
  const int w = tid >> 6;   // 0..7
  const int lane = tid & 63;
  const int wm = (w & 1) << 6;   // wave row offset (0/64)
  const int wn = (w >> 1) << 5;  // wave col offset (0/32/64/96)

  f32x4 acc[4][2];
#pragma unroll
  for (int mt = 0; mt < 4; mt++)
#pragma unroll
    for (int nt2 = 0; nt2 < 2; nt2++) acc[mt][nt2] = (f32x4){0.f, 0.f, 0.f, 0.f};

  const int i0 = w << 1;  // this wave's two staging issues per plane

#define STAGE(BUF, K0)                                                    \
  do {                                                                    \
    _Float16* base_ = &lds[BUF][0][0];                                    \
    _Pragma("unroll") for (int j = 0; j < 2; j++) {                       \
      int i = i0 + j;                                                     \
      int idx = (i << 6) + lane;                                          \
      int row = idx >> 3;                                                 \
      int cl = ((idx & 7) ^ (row & 7)) << 3;                              \
      size_t aoff = (size_t)(mBase + row) * lda + (K0) + cl;              \
      size_t boff = (size_t)(nBase + row) * K + (K0) + cl;                \
      async_ld16(base_ + (i << 9), Ah + aoff);                            \
      async_ld16(base_ + 8192 + (i << 9), Al + aoff);                     \
      async_ld16(base_ + 16384 + (i << 9), Bh + boff);                    \
      async_ld16(base_ + 24576 + (i << 9), Bl + boff);                    \
    }                                                                     \
  } while (0)

  STAGE(0, 0);
  asm volatile("s_waitcnt vmcnt(0)" ::: "memory");
  __builtin_amdgcn_s_barrier();

  const int nch = K >> 6;
  int cur = 0;
#pragma unroll 1
  for (int c = 0; c < nch; c++) {
    const bool pre = (c + 1 < nch);
    if (pre) {
      STAGE(cur ^ 1, (c + 1) << 6);  // prefetch next chunk (stays in flight)
      asm volatile("s_waitcnt vmcnt(8)" ::: "memory");  // chunk c's loads done
    } else {
      asm volatile("s_waitcnt vmcnt(0)" ::: "memory");
    }
    __builtin_amdgcn_s_barrier();  // all waves' chunk-c staging visible
    const _Float16* ash = &lds[cur][0][0];
    const _Float16* asl = &lds[cur][1][0];
    const _Float16* bsh = &lds[cur][2][0];
    const _Float16* bsl = &lds[cur][3][0];
#pragma unroll
    for (int q = 0; q < 2; q++) {
      f16x8 afh[4], afl[4], bfh[2], bfl[2];
#pragma unroll
      for (int mt = 0; mt < 4; mt++) {
        int row = wm + (mt << 4) + (lane & 15);
        int p = ((q << 2) + (lane >> 4)) ^ (row & 7);
        afh[mt] = *(const f16x8*)&ash[(row << 6) + (p << 3)];
        afl[mt] = *(const f16x8*)&asl[(row << 6) + (p << 3)];
      }
#pragma unroll
      for (int nt2 = 0; nt2 < 2; nt2++) {
        int row = wn + (nt2 << 4) + (lane & 15);
        int p = ((q << 2) + (lane >> 4)) ^ (row & 7);
        bfh[nt2] = *(const f16x8*)&bsh[(row << 6) + (p << 3)];
        bfl[nt2] = *(const f16x8*)&bsl[(row << 6) + (p << 3)];
      }
      __builtin_amdgcn_s_setprio(1);
#pragma unroll
      for (int mt = 0; mt < 4; mt++)
#pragma unroll
        for (int nt2 = 0; nt2 < 2; nt2++) {
          // swapped operands: D[n][m] — same products, same order, lane regs
          // become 4 consecutive n-columns (vectorized C-write below)
          acc[mt][nt2] = __builtin_amdgcn_mfma_f32_16x16x32_f16(bfh[nt2], afh[mt], acc[mt][nt2], 0, 0, 0);
          acc[mt][nt2] = __builtin_amdgcn_mfma_f32_16x16x32_f16(bfh[nt2], afl[mt], acc[mt][nt2], 0, 0, 0);
          acc[mt][nt2] = __builtin_amdgcn_mfma_f32_16x16x32_f16(bfl[nt2], afh[mt], acc[mt][nt2], 0, 0, 0);
        }
      __builtin_amdgcn_s_setprio(0);
    }
    __builtin_amdgcn_s_barrier();  // LDS buf consumed before next-iter STAGE
    cur ^= 1;
  }
#undef STAGE

  // Swapped D layout: A-side (= Bt rows = n) -> row dim: n_off = (lane>>4)*4+reg;
  // B-side (= A rows = m) -> col dim: m_off = lane&15.
  // Lane's 4 regs = 4 consecutive n -> one float4 store per acc.
  int q4 = lane >> 4, mloc = lane & 15;
  float* G = op.G;
#pragma unroll
  for (int mt = 0; mt < 4; mt++)
#pragma unroll
    for (int nt2 = 0; nt2 < 2; nt2++) {
      int row = mBase + wm + (mt << 4) + mloc;
      int col = nBase + wn + (nt2 << 4) + (q4 << 2);
      *(float4*)&G[(size_t)row * G4_ + col] = *(float4*)&acc[mt][nt2];
    }
}

// ---------------- cell phase: up to 2 independent cells, blockIdx.x>>10 selects ----

__device__ __forceinline__ void block_reduce(float* v, int n, float* sred, int tid) {
  int lane = tid & 63, w = tid >> 6;
  for (int off = 32; off > 0; off >>= 1)
    for (int i = 0; i < n; i++) v[i] += __shfl_down(v[i], off, 64);
  if (lane == 0)
    for (int i = 0; i < n; i++) sred[w * 4 + i] = v[i];
  __syncthreads();
  if (tid == 0)
    for (int i = 0; i < n; i++) sred[16 + i] = sred[i] + sred[4 + i] + sred[8 + i] + sred[12 + i];
  __syncthreads();
  for (int i = 0; i < n; i++) v[i] = sred[16 + i];
}

__device__ __forceinline__ float sigm(float x) { return 1.f / (1.f + expf(-x)); }

struct CellOp {
  const float* Gx;
  const float* Gh;
  const float* bias;
  const float* kg;
  const float* kb;
  const float* rg;
  const float* rb;
  const float* sg;
  const float* sb;
  float* cS;
  _Float16* hP;   // hi plane; lo at +B_*U_
  float* outb;    // layer-1 only (else null)
  int step;
};
struct C2Pack {
  CellOp op[2];
  const int* nt;
};

// After compaction every surviving row is active (mask==1): the mask logic and
// the old-state reads disappear; rows >= nt[step] exit immediately.
__global__ __launch_bounds__(256) void cell_phase(C2Pack P) {
  CellOp cp = P.op[blockIdx.x >> 10];
  int b = blockIdx.x & (B_ - 1);
  if (b >= P.nt[cp.step]) return;  // block-uniform
  int tid = threadIdx.x;
  __shared__ float sred[20];
  const float* gx = cp.Gx + (size_t)b * G4_;
  const float* gh = cp.Gh + (size_t)b * G4_;
  float vx[8], vh[8];
  float s[4] = {0.f, 0.f, 0.f, 0.f};
#pragma unroll
  for (int i = 0; i < 8; i++) {
    int col = tid + (i << 8);
    float a = gx[col], d = gh[col];
    vx[i] = a;
    vh[i] = d;
    s[0] += a;
    s[1] += a * a;
    s[2] += d;
    s[3] += d * d;
  }
  block_reduce(s, 4, sred, tid);
  const float inv = 1.f / 2048.f;
  float m1 = s[0] * inv, m2 = s[2] * inv;
  float rs1 = rsqrtf(fmaxf(s[1] * inv - m1 * m1, 0.f) + EPS_);
  float rs2 = rsqrtf(fmaxf(s[3] * inv - m2 * m2, 0.f) + EPS_);
  float z[8];
#pragma unroll
  for (int i = 0; i < 8; i++) {
    int col = tid + (i << 8);
    z[i] = (vx[i] - m1) * rs1 * cp.kg[col] + cp.kb[col] +
           (vh[i] - m2) * rs2 * cp.rg[col] + cp.rb[col] + cp.bias[col];
  }
  // cols: i=0,1 -> i-gate (j0,j1); 2,3 -> f; 4,5 -> g; 6,7 -> o
  int j0 = tid, j1 = tid + 256;
  size_t base = (size_t)b * U_;
  _Float16* hHi = cp.hP;
  _Float16* hLo = cp.hP + (size_t)B_ * U_;
  float co0 = cp.cS[base + j0], co1 = cp.cS[base + j1];
  float cn0 = sigm(z[2]) * co0 + sigm(z[0]) * tanhf(z[4]);
  float cn1 = sigm(z[3]) * co1 + sigm(z[1]) * tanhf(z[5]);
  float t2[2] = {cn0 + cn1, cn0 * cn0 + cn1 * cn1};
  block_reduce(t2, 2, sred, tid);
  const float invU = 1.f / 512.f;
  float mc = t2[0] * invU;
  float rsc = rsqrtf(fmaxf(t2[1] * invU - mc * mc, 0.f) + EPS_);
  float cl0 = (cn0 - mc) * rsc * cp.sg[j0] + cp.sb[j0];
  float cl1 = (cn1 - mc) * rsc * cp.sg[j1] + cp.sb[j1];
  float hn0 = sigm(z[6]) * tanhf(cl0);
  float hn1 = sigm(z[7]) * tanhf(cl1);
  _Float16 hh0 = (_Float16)hn0, hh1 = (_Float16)hn1;
  hHi[base + j0] = hh0;
  hLo[base + j0] = (_Float16)(hn0 - (float)hh0);
  hHi[base + j1] = hh1;
  hLo[base + j1] = (_Float16)(hn1 - (float)hh1);
  cp.cS[base + j0] = cl0;
  cp.cS[base + j1] = cl1;
  if (cp.outb) {  // layer-1: out row freezes at the last active step
    cp.outb[base + j0] = hn0;
    cp.outb[base + j1] = hn1;
  }
}

// ---------------- final dense + softmax (scatter through perm) ----------------
__global__ __launch_bounds__(64) void dense_softmax_kernel(const float* __restrict__ outb,
                                                           const float* __restrict__ Wd,
                                                           const float* __restrict__ bd,
                                                           const int* __restrict__ perm,
                                                           float* __restrict__ o) {
  int b = blockIdx.x, lane = threadIdx.x;
  __shared__ float sl[16];
  int col = lane & 15, kg = lane >> 4;
  float acc = 0.f;
  if (col < C_) {
    for (int k = kg; k < U_; k += 4) acc += outb[(size_t)b * U_ + k] * Wd[(size_t)k * C_ + col];
  }
  acc += __shfl_down(acc, 16, 64);
  acc += __shfl_down(acc, 32, 64);
  if (lane < C_) sl[lane] = acc + bd[lane];
  __syncthreads();
  if (lane < C_) {
    float mx = sl[0];
    for (int i = 1; i < C_; i++) mx = fmaxf(mx, sl[i]);
    float ssum = 0.f;
    for (int i = 0; i < C_; i++) ssum += expf(sl[i] - mx);
    o[(size_t)perm[b] * C_ + lane] = expf(sl[lane] - mx) / ssum;
  }
}

// ---------------- host ----------------

extern "C" void kernel_launch(void* const* d_in, const int* in_sizes, int n_in,
                              void* d_out, int out_size, void* d_ws, size_t ws_size,
                              hipStream_t stream) {
  const float* x = (const float*)d_in[0];
  const int* mask = (const int*)d_in[1];
  const float* W0 = (const float*)d_in[2];
  const float* R0 = (const float*)d_in[3];
  const float* b0 = (const float*)d_in[4];
  const float* kg0 = (const float*)d_in[5];
  const float* kb0 = (const float*)d_in[6];
  const float* rg0 = (const float*)d_in[7];
  const float* rb0 = (const float*)d_in[8];
  const float* sg0 = (const float*)d_in[9];
  const float* sb0 = (const float*)d_in[10];
  const float* W1 = (const float*)d_in[11];
  const float* R1 = (const float*)d_in[12];
  const float* b1 = (const float*)d_in[13];
  const float* kg1 = (const float*)d_in[14];
  const float* kb1 = (const float*)d_in[15];
  const float* rg1 = (const float*)d_in[16];
  const float* rb1 = (const float*)d_in[17];
  const float* sg1 = (const float*)d_in[18];
  const float* sb1 = (const float*)d_in[19];
  const float* Wd = (const float*)d_in[20];
  const float* bd = (const float*)d_in[21];
  float* out = (float*)d_out;

  char* w = (char*)d_ws;
  size_t o = 0;
  auto alloc = [&](size_t bytes) {
    size_t r = o;
    o += (bytes + 255) & ~(size_t)255;
    return r;
  };
  // zero region (contiguous, first): states + G0h (must be 0 for cell0(0))
  size_t o_c0s = alloc((size_t)B_ * U_ * 4);
  size_t o_c1s = alloc((size_t)B_ * U_ * 4);
  size_t o_outf = alloc((size_t)B_ * U_ * 4);
  size_t o_h0p = alloc((size_t)B_ * U_ * 2 * 2);  // hi + lo contiguous
  size_t o_h1p = alloc((size_t)B_ * U_ * 2 * 2);
  size_t o_G0h = alloc((size_t)B_ * G4_ * 4);
  size_t zero_bytes = o;
  size_t o_xh = alloc((size_t)T_ * B_ * FP_ * 2 * 2);  // hi + lo
  size_t o_W0t = alloc((size_t)G4_ * FP_ * 2 * 2);
  size_t o_R0t = alloc((size_t)G4_ * U_ * 2 * 2);
  size_t o_W1t = alloc((size_t)G4_ * U_ * 2 * 2);
  size_t o_R1t = alloc((size_t)G4_ * U_ * 2 * 2);
  size_t o_G0x = alloc((size_t)B_ * G4_ * 4);
  size_t o_G1x = alloc((size_t)B_ * G4_ * 4);
  size_t o_G1h = alloc((size_t)B_ * G4_ * 4);
  size_t o_perm = alloc((size_t)B_ * 4);
  size_t o_nt = alloc((size_t)T_ * 4);
  (void)ws_size;

  float* c0s = (float*)(w + o_c0s);
  float* c1s = (float*)(w + o_c1s);
  float* outf = (float*)(w + o_outf);
  _Float16* h0p = (_Float16*)(w + o_h0p);
  _Float16* h1p = (_Float16*)(w + o_h1p);
  float* G0h = (float*)(w + o_G0h);
  _Float16* xh = (_Float16*)(w + o_xh);
  _Float16* W0t = (_Float16*)(w + o_W0t);
  _Float16* R0t = (_Float16*)(w + o_R0t);
  _Float16* W1t = (_Float16*)(w + o_W1t);
  _Float16* R1t = (_Float16*)(w + o_R1t);
  float* G0x = (float*)(w + o_G0x);
  float* G1x = (float*)(w + o_G1x);
  float* G1h = (float*)(w + o_G1h);
  int* perm = (int*)(w + o_perm);
  int* ntp = (int*)(w + o_nt);

  hipMemsetAsync(w, 0, zero_bytes, stream);

  prep_kernel<<<1, 1024, 0, stream>>>(mask, perm, ntp);

  {
    size_t chunks = (size_t)T_ * B_ * (FP_ / 8);
    cast_x_kernel<<<dim3((unsigned)(chunks / 256)), 256, 0, stream>>>(
        x, perm, ntp, xh, xh + (size_t)T_ * B_ * FP_);
  }
  cast_w_kernel<<<dim3(G4_ / 32, FP_ / 32), 256, 0, stream>>>(
      W0, W0t, W0t + (size_t)G4_ * FP_, F_, G4_, FP_);
  cast_w_kernel<<<dim3(G4_ / 32, U_ / 32), 256, 0, stream>>>(
      R0, R0t, R0t + (size_t)G4_ * U_, U_, G4_, U_);
  cast_w_kernel<<<dim3(G4_ / 32, U_ / 32), 256, 0, stream>>>(
      W1, W1t, W1t + (size_t)G4_ * U_, U_, G4_, U_);
  cast_w_kernel<<<dim3(G4_ / 32, U_ / 32), 256, 0, stream>>>(
      R1, R1t, R1t + (size_t)G4_ * U_, U_, G4_, U_);

  const size_t xLoOff = (size_t)T_ * B_ * FP_;
  const size_t hLoOff = (size_t)B_ * U_;

  auto xw_op = [&](int t) -> GemmOp {
    return GemmOp{xh + (size_t)t * B_ * FP_, W0t, G0x, FP_, FP_, xLoOff, t};
  };
  CellOp cell0op = {G0x, G0h, b0, kg0, kb0, rg0, rb0, sg0, sb0,
                    c0s, h0p, nullptr, 0};
  CellOp cell1op = {G1x, G1h, b1, kg1, kb1, rg1, rb1, sg1, sb1,
                    c1s, h1p, outf, 0};

  // ---- prime: G0x(0) = x0 @ W0 ; then cell0(0) (G0h is zeroed) ----
  {
    G4Pack P;
    P.nt = ntp;
    P.op[0] = xw_op(0);
    P.op[1] = P.op[0];
    P.op[2] = P.op[0];
    P.op[3] = P.op[0];
    gemm_phase<<<dim3(G4_ / 128, B_ / 128, 1), 512, 0, stream>>>(P);
    C2Pack CP;
    CP.nt = ntp;
    cell0op.step = 0;
    CP.op[0] = cell0op;
    CP.op[1] = cell0op;
    cell_phase<<<B_, 256, 0, stream>>>(CP);
  }

  // ---- steady loop: A(t) = GEMMs, B(t) = cells ----
  for (int t = 0; t < T_; t++) {
    bool more = (t < T_ - 1);
    G4Pack P;
    P.nt = ntp;
    P.op[0] = GemmOp{h0p, W1t, G1x, U_, U_, hLoOff, t};       // G1x(t) = h0(t) @ W1
    P.op[1] = GemmOp{h1p, R1t, G1h, U_, U_, hLoOff, t};       // G1h(t) = h1(t-1) @ R1
    if (more) {
      P.op[2] = GemmOp{h0p, R0t, G0h, U_, U_, hLoOff, t + 1};  // G0h(t+1) = h0(t) @ R0
      P.op[3] = xw_op(t + 1);                                  // G0x(t+1) = x(t+1) @ W0
    } else {
      P.op[2] = P.op[0];
      P.op[3] = P.op[0];
    }
    gemm_phase<<<dim3(G4_ / 128, B_ / 128, more ? 4 : 2), 512, 0, stream>>>(P);

    C2Pack CP;
    CP.nt = ntp;
    cell1op.step = t;
    CP.op[0] = cell1op;
    cell0op.step = t + 1;
    CP.op[1] = more ? cell0op : cell1op;
    cell_phase<<<more ? 2 * B_ : B_, 256, 0, stream>>>(CP);
  }

  dense_softmax_kernel<<<B_, 64, 0, stream>>>(outf, Wd, bd, perm, out);
}